// Round 9
// baseline (1055.523 us; speedup 1.0000x reference)
//
#include <hip/hip_runtime.h>
#include <hip/hip_bf16.h>
#include <stdint.h>

// AspectSent forward on MI355X.
// Pipeline: k_prep (fused embed/cvt/wfrag/w2/zero/bias-merge) -> [gi GEMM(+cb)
// -> persistent GRU]x2 -> im2col -> conv GEMM(+relu) -> epilogue chain.
// All matmuls bf16 MFMA 16x16x32, f32 accumulate.
// GRU v4: ONE barrier/step. whh columns permuted so wave w's 96 cols are the
// (r,z,n) triples for j in [32w,32w+32) -> gate reads only own-wave gh2 (no
// barrier between MFMA and gate). h double-buffered in LDS (removes the WAR
// race barrier#1 guarded; stale parity on frozen rows is dead data). gh2 is
// 4 rows, written by lanes 0-15 only. bih+bhh merged into gi GEMM bias for
// r,z gates (exact); n gate keeps one bhh_n register.

#define TT 100
#define BB 128

typedef short s16;
typedef unsigned int u32;
typedef __attribute__((ext_vector_type(8))) short s16x8;
typedef __attribute__((ext_vector_type(4))) float f32x4;

__device__ __forceinline__ float bf2f(s16 s) {
  return __uint_as_float(((unsigned)(unsigned short)s) << 16);
}
__device__ __forceinline__ s16 f2bf(float f) {
  __hip_bfloat16 h = __float2bfloat16(f);
  return *(s16*)&h;
}
__device__ __forceinline__ float sigf(float x) { return 1.f / (1.f + __expf(-x)); }
__device__ __forceinline__ float tanhfast(float x) { return 2.f / (1.f + __expf(-2.f * x)) - 1.f; }
__device__ __forceinline__ float lse2(float a, float b) {
  float m = fmaxf(a, b);
  return m + logf(expf(a - m) + expf(b - m));
}

// ---------------- fused prep ----------------
__global__ void k_prep(const float* __restrict__ wih0f, const float* __restrict__ wih0b,
                       const float* __restrict__ wih1f, const float* __restrict__ wih1b,
                       const float* __restrict__ whh0f, const float* __restrict__ whh0b,
                       const float* __restrict__ whh1f, const float* __restrict__ whh1b,
                       const float* __restrict__ convw,
                       const int* __restrict__ sents, const int* __restrict__ masks,
                       const float* __restrict__ wemb, const float* __restrict__ memb,
                       const float* __restrict__ bih0f, const float* __restrict__ bhh0f,
                       const float* __restrict__ bih0b, const float* __restrict__ bhh0b,
                       const float* __restrict__ bih1f, const float* __restrict__ bhh1f,
                       const float* __restrict__ bih1b, const float* __restrict__ bhh1b,
                       s16* __restrict__ cwih0f, s16* __restrict__ cwih0b,
                       s16* __restrict__ cwih1f, s16* __restrict__ cwih1b,
                       s16* __restrict__ wf0f, s16* __restrict__ wf0b,
                       s16* __restrict__ wf1f, s16* __restrict__ wf1b,
                       s16* __restrict__ w2, s16* __restrict__ x0,
                       uint4* __restrict__ x2z,
                       float* __restrict__ cb0f, float* __restrict__ cb0b,
                       float* __restrict__ cb1f, float* __restrict__ cb1b) {
  const int stride = gridDim.x * 256;
  const int base = blockIdx.x * 256 + threadIdx.x;

  // merged gi-GEMM bias: bih + bhh for r,z gates (cols<512), bih for n gate
  for (int idx = base; idx < 768; idx += stride) {
    float e = (idx < 512) ? 1.f : 0.f;
    cb0f[idx] = bih0f[idx] + e * bhh0f[idx];
    cb0b[idx] = bih0b[idx] + e * bhh0b[idx];
    cb1f[idx] = bih1f[idx] + e * bhh1f[idx];
    cb1b[idx] = bih1b[idx] + e * bhh1b[idx];
  }
  // wih layer0: f32 (768x350) -> bf16 (768x352) zero-padded
  for (int idx = base; idx < 768 * 352; idx += stride) {
    int n = idx / 352, k = idx % 352;
    cwih0f[idx] = (k < 350) ? f2bf(wih0f[n * 350 + k]) : (s16)0;
    cwih0b[idx] = (k < 350) ? f2bf(wih0b[n * 350 + k]) : (s16)0;
  }
  // wih layer1: straight cvt (768x512)
  for (int idx = base; idx < 393216; idx += stride) {
    cwih1f[idx] = f2bf(wih1f[idx]);
    cwih1b[idx] = f2bf(wih1b[idx]);
  }
  // whh -> MFMA B-fragment layout, columns PERMUTED to gate-triple interleave:
  // B col (96w + jg), jg = 3*jl + gate  ->  whh row (gate*256 + 32w + jl)
  for (int idx = base; idx < 196608; idx += stride) {
    int w = idx / 24576, rem = idx % 24576;
    int f = rem / 512, rem2 = rem % 512;
    int l = rem2 / 8, i = rem2 % 8;
    int nt = f / 8, kt = f % 8;
    int jg = 16 * nt + (l & 15);
    int jl = jg / 3, gate = jg - 3 * jl;
    int src = (gate * 256 + 32 * w + jl) * 256 + 32 * kt + 8 * (l >> 4) + i;
    wf0f[idx] = f2bf(whh0f[src]);
    wf0b[idx] = f2bf(whh0b[src]);
    wf1f[idx] = f2bf(whh1f[src]);
    wf1b[idx] = f2bf(whh1b[src]);
  }
  // conv_w (512,512,3) -> w2 [512][1536], w2[o][w*512+i] = conv_w[o,i,w]
  for (int idx = base; idx < 786432; idx += stride) {
    int o = idx / 1536, c = idx % 1536;
    int w = c / 512, i = c % 512;
    w2[idx] = f2bf(convw[o * 1536 + i * 3 + w]);
  }
  // embed
  for (int idx = base; idx < BB * TT * 352; idx += stride) {
    int c = idx % 352, bt = idx / 352;
    float v;
    if (c < 300)      v = wemb[(size_t)sents[bt] * 300 + c];
    else if (c < 350) v = memb[masks[bt] * 50 + (c - 300)];
    else              v = 0.f;
    x0[idx] = f2bf(v);
  }
  // zero x2 (conv reads t >= len rows; GRU1 writes only t < len)
  for (int idx = base; idx < 819200; idx += stride)
    x2z[idx] = make_uint4(0u, 0u, 0u, 0u);
}

// ---------------- GEMM: C[M,N](bf16) = A[M,K](bf16) * B[N,K](bf16)^T ----------------
__global__ __launch_bounds__(256) void k_gemm(const s16* __restrict__ A, const s16* __restrict__ Bm,
                                              s16* __restrict__ C, int K, int ldA, int ldB, int ldC,
                                              const float* __restrict__ bias, int relu) {
  __shared__ s16 As[128 * 32];
  __shared__ s16 Bs[128 * 32];
  const int t = threadIdx.x, w = t >> 6, l = t & 63;
  const size_t m0 = (size_t)blockIdx.x * 128, n0 = (size_t)blockIdx.y * 128;
  f32x4 zero = {0.f, 0.f, 0.f, 0.f};
  f32x4 acc[4][4];
#pragma unroll
  for (int i = 0; i < 4; ++i)
#pragma unroll
    for (int j = 0; j < 4; ++j) acc[i][j] = zero;

  for (int kb = 0; kb < K; kb += 32) {
    __syncthreads();
    {
      const s16* gA = A + (m0 + (t >> 1)) * (size_t)ldA + kb + 16 * (t & 1);
      *(s16x8*)&As[(t >> 1) * 32 + 16 * (t & 1)]     = *(const s16x8*)gA;
      *(s16x8*)&As[(t >> 1) * 32 + 16 * (t & 1) + 8] = *(const s16x8*)(gA + 8);
      const s16* gB = Bm + (n0 + (t >> 1)) * (size_t)ldB + kb + 16 * (t & 1);
      *(s16x8*)&Bs[(t >> 1) * 32 + 16 * (t & 1)]     = *(const s16x8*)gB;
      *(s16x8*)&Bs[(t >> 1) * 32 + 16 * (t & 1) + 8] = *(const s16x8*)(gB + 8);
    }
    __syncthreads();
    s16x8 a[4], b[4];
#pragma unroll
    for (int i = 0; i < 4; ++i)
      a[i] = *(const s16x8*)&As[(64 * (w >> 1) + 16 * i + (l & 15)) * 32 + 8 * (l >> 4)];
#pragma unroll
    for (int j = 0; j < 4; ++j)
      b[j] = *(const s16x8*)&Bs[(64 * (w & 1) + 16 * j + (l & 15)) * 32 + 8 * (l >> 4)];
#pragma unroll
    for (int i = 0; i < 4; ++i)
#pragma unroll
      for (int j = 0; j < 4; ++j)
        acc[i][j] = __builtin_amdgcn_mfma_f32_16x16x32_bf16(a[i], b[j], acc[i][j], 0, 0, 0);
  }
#pragma unroll
  for (int i = 0; i < 4; ++i)
#pragma unroll
    for (int j = 0; j < 4; ++j)
#pragma unroll
      for (int r = 0; r < 4; ++r) {
        size_t row = m0 + 64 * (w >> 1) + 16 * i + 4 * (l >> 4) + r;
        size_t col = n0 + 64 * (w & 1) + 16 * j + (l & 15);
        float v = acc[i][j][r];
        if (bias) v += bias[col];
        if (relu) v = fmaxf(v, 0.f);
        C[row * (size_t)ldC + col] = f2bf(v);
      }
}

// ---------------- persistent GRU v4 (1 barrier/step) ----------------
// grid (32,2): 4 batch rows/block. 512 thr = 8 waves, wave w owns gate
// triples for j in [32w,32w+32) via permuted whh cols. h double-buffered.
__global__ __launch_bounds__(512, 2) void k_gru(
    const s16* __restrict__ gi_f, const s16* __restrict__ gi_b,
    const s16* __restrict__ wf_f, const s16* __restrict__ wf_b,
    const float* __restrict__ bhh_f, const float* __restrict__ bhh_b,
    const int* __restrict__ lens, s16* __restrict__ out) {
  const int g = blockIdx.x;
  const int dir = blockIdx.y;
  const int tid = threadIdx.x, wid = tid >> 6, l = tid & 63;
  const s16* gi = dir ? gi_b : gi_f;
  const s16* wf = dir ? wf_b : wf_f;
  const float* bhh = dir ? bhh_b : bhh_f;
  const int col_off = dir ? 256 : 0;
  const int b0 = g * 4;

  __shared__ __align__(16) float gh2[4 * 772];     // only rows 0-3 exist now
  __shared__ __align__(16) s16 hb[2 * 16 * 264];   // double-buffered h (bf16)
  __shared__ int s_len[4];

  // whh B-fragments, register-resident (192 regs; unified VGPR/AGPR file)
  s16x8 wv[48];
#pragma unroll
  for (int f = 0; f < 48; ++f)
    wv[f] = *(const s16x8*)&wf[((size_t)(wid * 48 + f)) * 512 + l * 8];

  const int jl = l & 31;            // j within wave's 32-block
  const int jg = 32 * wid + jl;     // global j (0..255)
  const float bhn = bhh[512 + jg];  // n-gate hidden bias (r,z merged in GEMM)

  for (int i = tid; i < 2 * 16 * 264; i += 512) hb[i] = 0;
  if (tid < 4) s_len[tid] = lens[b0 + tid];
  __syncthreads();

  const int smax = s_len[0];        // lens sorted descending
  const int ra = l >> 5;            // item rows: ra and ra+2
  const int rb = ra + 2;
  const int lena = s_len[ra], lenb = s_len[rb];
  const s16* gA = gi + (size_t)(b0 + ra) * TT * 768 + jg;
  const s16* gB = gi + (size_t)(b0 + rb) * TT * 768 + jg;
  s16* oA = out + (size_t)(b0 + ra) * TT * 512 + col_off + jg;
  s16* oB = out + (size_t)(b0 + rb) * TT * 512 + col_off + jg;
  float hpa = 0.f, hpb = 0.f;

  // prologue: prefetch gi for s=0 (len >= 5 always)
  s16 qar, qaz, qan, qbr, qbz, qbn;
  int pa = dir ? (lena - 1) : 0;
  { const s16* gp = gA + (size_t)pa * 768; qar = gp[0]; qaz = gp[256]; qan = gp[512]; }
  int pb = dir ? (lenb - 1) : 0;
  { const s16* gp = gB + (size_t)pb * 768; qbr = gp[0]; qbz = gp[256]; qbn = gp[512]; }

  for (int s = 0; s < smax; ++s) {
    const s16* hr = hb + (s & 1) * (16 * 264);        // read buffer
    s16* hw = hb + ((s + 1) & 1) * (16 * 264);        // write buffer

    // ---- issue prefetch for step s+1 ----
    s16 nar = 0, naz = 0, nan_ = 0, nbr = 0, nbz = 0, nbn = 0;
    int npa = 0, npb = 0;
    if (s + 1 < lena) {
      npa = dir ? (lena - 2 - s) : (s + 1);
      const s16* gp = gA + (size_t)npa * 768;
      nar = gp[0]; naz = gp[256]; nan_ = gp[512];
    }
    if (s + 1 < lenb) {
      npb = dir ? (lenb - 2 - s) : (s + 1);
      const s16* gp = gB + (size_t)npb * 768;
      nbr = gp[0]; nbz = gp[256]; nbn = gp[512];
    }

    // ---- MFMA phase: gh = h @ whh^T (permuted cols) ----
    f32x4 zero = {0.f, 0.f, 0.f, 0.f};
    f32x4 acc[6];
#pragma unroll
    for (int nt = 0; nt < 6; ++nt) acc[nt] = zero;
#pragma unroll
    for (int kt = 0; kt < 8; ++kt) {
      s16x8 a = *(const s16x8*)&hr[(l & 15) * 264 + 32 * kt + 8 * (l >> 4)];
#pragma unroll
      for (int nt = 0; nt < 6; ++nt)
        acc[nt] = __builtin_amdgcn_mfma_f32_16x16x32_bf16(a, wv[nt * 8 + kt], acc[nt], 0, 0, 0);
    }
    // epilogue: only rows 0-3 are real (lanes 0-15 hold them)
    if (l < 16) {
#pragma unroll
      for (int nt = 0; nt < 6; ++nt) {
        int col = 96 * wid + 16 * nt + l;
#pragma unroll
        for (int r = 0; r < 4; ++r)
          gh2[r * 772 + col] = acc[nt][r];
      }
    }
    // ---- gate phase: own-wave gh2 region only (no barrier needed) ----
    {
      int cb = 96 * wid + 3 * jl;
      if (s < lena) {
        float g0 = gh2[ra * 772 + cb];
        float g1 = gh2[ra * 772 + cb + 1];
        float g2 = gh2[ra * 772 + cb + 2];
        float rr = sigf(bf2f(qar) + g0);
        float zz = sigf(bf2f(qaz) + g1);
        float nn = tanhfast(bf2f(qan) + rr * (g2 + bhn));
        hpa = (1.f - zz) * nn + zz * hpa;
        s16 hv = f2bf(hpa);
        hw[ra * 264 + jg] = hv;
        oA[(size_t)pa * 512] = hv;
      } else if (s == lena) {
        hw[ra * 264 + jg] = f2bf(hpa);   // keep frozen h in both buffers
      }
      if (s < lenb) {
        float g0 = gh2[rb * 772 + cb];
        float g1 = gh2[rb * 772 + cb + 1];
        float g2 = gh2[rb * 772 + cb + 2];
        float rr = sigf(bf2f(qbr) + g0);
        float zz = sigf(bf2f(qbz) + g1);
        float nn = tanhfast(bf2f(qbn) + rr * (g2 + bhn));
        hpb = (1.f - zz) * nn + zz * hpb;
        s16 hv = f2bf(hpb);
        hw[rb * 264 + jg] = hv;
        oB[(size_t)pb * 512] = hv;
      } else if (s == lenb) {
        hw[rb * 264 + jg] = f2bf(hpb);
      }
    }
    __syncthreads();
    qar = nar; qaz = naz; qan = nan_; pa = npa;
    qbr = nbr; qbz = nbz; qbn = nbn; pb = npb;
  }
}

// ---------------- im2col for conv (k=3, pad 1) ----------------
__global__ void k_im2col(const s16* __restrict__ x2, s16* __restrict__ A2) {
  int idx = blockIdx.x * 256 + threadIdx.x;           // 12800*1536/8
  if (idx >= 2457600) return;
  size_t e = (size_t)idx * 8;
  int bt = (int)(e / 1536), c = (int)(e % 1536);
  int w = c / 512, i = c % 512;
  int b = bt / TT, t = bt % TT;
  int ts = t + w - 1;
  s16x8 v;
  if (ts >= 0 && ts < TT) v = *(const s16x8*)&x2[(size_t)(b * TT + ts) * 512 + i];
  else { s16x8 z = {0,0,0,0,0,0,0,0}; v = z; }
  *(s16x8*)&A2[e] = v;
}

// ---------------- small epilogue kernels ----------------
__global__ void k_avg(const s16* __restrict__ ctx, const int* __restrict__ masks,
                      float* __restrict__ avg) {
  int b = blockIdx.x, t = threadIdx.x;  // 256
  float a0 = 0, a1 = 0, ms = 0;
  for (int tt = 0; tt < TT; ++tt) {
    float mf = (float)masks[b * TT + tt];
    ms += mf;
    if (mf != 0.f) {
      a0 += mf * bf2f(ctx[(size_t)(b * TT + tt) * 512 + t]);
      a1 += mf * bf2f(ctx[(size_t)(b * TT + tt) * 512 + 256 + t]);
    }
  }
  avg[b * 512 + t] = a0 / ms;
  avg[b * 512 + 256 + t] = a1 / ms;
}

__global__ void k_tri(const s16* __restrict__ ctx, const float* __restrict__ avg,
                      const float* __restrict__ triw, const float* __restrict__ trib,
                      float* __restrict__ tri) {
  int gw = (blockIdx.x * 256 + threadIdx.x) >> 6;
  int l = threadIdx.x & 63;
  if (gw >= BB * TT) return;
  int b = gw / TT;
  float a0 = 0, a1 = 0;
  for (int it = 0; it < 16; ++it) {
    int k = l + 64 * it;
    float v = (k < 512) ? bf2f(ctx[(size_t)gw * 512 + k]) : avg[b * 512 + k - 512];
    a0 += v * triw[k];
    a1 += v * triw[1024 + k];
  }
  for (int off = 32; off; off >>= 1) {
    a0 += __shfl_down(a0, off, 64);
    a1 += __shfl_down(a1, off, 64);
  }
  if (l == 0) {
    tri[gw * 2]     = a0 + trib[0];
    tri[gw * 2 + 1] = a1 + trib[1];
  }
}

__global__ void k_crf(const float* __restrict__ tri, const int* __restrict__ lens,
                      const float* __restrict__ trans, float* __restrict__ alphas,
                      float* __restrict__ sp, float* __restrict__ sp_sum) {
  int b = threadIdx.x;  // 128 threads, 1 block
  int L = lens[b];
  float t00 = trans[0], t01 = trans[1], t10 = trans[2], t11 = trans[3];
  const float* f = tri + b * 2 * TT;
  float* al = alphas + b * 2 * TT;
  float a0 = f[0], a1 = f[1];
  al[0] = a0; al[1] = a1;
  for (int t = 1; t < TT; ++t) {
    if (t < L) {
      float n0 = lse2(a0 + t00, a1 + t10) + f[2 * t];
      float n1 = lse2(a0 + t01, a1 + t11) + f[2 * t + 1];
      a0 = n0; a1 = n1;
    }
    al[2 * t] = a0; al[2 * t + 1] = a1;
  }
  float logZ = lse2(a0, a1);
  float b0 = 0.f, b1 = 0.f, ssum = 0.f;
  {
    float v = (TT - 1 < L) ? expf(al[2 * (TT - 1) + 1] - logZ) : 0.f;
    sp[b * TT + TT - 1] = v; ssum += v;
  }
  for (int t = TT - 2; t >= 0; --t) {
    float fn0 = f[2 * (t + 1)], fn1 = f[2 * (t + 1) + 1];
    float c0 = lse2(t00 + fn0 + b0, t01 + fn1 + b1);
    float c1 = lse2(t10 + fn0 + b0, t11 + fn1 + b1);
    if (t >= L - 1) { b0 = 0.f; b1 = 0.f; } else { b0 = c0; b1 = c1; }
    float v = (t < L) ? expf(al[2 * t + 1] + b1 - logZ) : 0.f;
    sp[b * TT + t] = v; ssum += v;
  }
  sp_sum[b] = ssum;
}

__global__ void k_sentv(const s16* __restrict__ ctx, const float* __restrict__ sp,
                        float* __restrict__ sv) {
  int b = blockIdx.x, t = threadIdx.x;  // 256
  float a0 = 0, a1 = 0;
  for (int tt = 0; tt < TT; ++tt) {
    float w = sp[b * TT + tt];
    if (w != 0.f) {
      a0 += w * bf2f(ctx[(size_t)(b * TT + tt) * 512 + t]);
      a1 += w * bf2f(ctx[(size_t)(b * TT + tt) * 512 + 256 + t]);
    }
  }
  sv[b * 512 + t] = a0;
  sv[b * 512 + 256 + t] = a1;
}

__global__ void k_final(const float* __restrict__ sv, const float* __restrict__ sp_sum,
                        const int* __restrict__ labels, const float* __restrict__ labw,
                        const float* __restrict__ labb, const float* __restrict__ trans,
                        float* __restrict__ out) {
  __shared__ float red[128];
  int b = threadIdx.x;  // 128
  float g = sp_sum[b] * 0.5f;
  g = fminf(fmaxf(g, 1e-4f), 1e5f);
  float s[3];
  for (int c = 0; c < 3; ++c) {
    float a = 0.f;
    for (int h = 0; h < 512; ++h) a += sv[b * 512 + h] * labw[c * 512 + h];
    s[c] = a / g + labb[c];
  }
  float m = fmaxf(s[0], fmaxf(s[1], s[2]));
  float lse = m + logf(expf(s[0] - m) + expf(s[1] - m) + expf(s[2] - m));
  red[b] = -(s[labels[b]] - lse);
  __syncthreads();
  if (b == 0) {
    float acc = 0.f, sn = 0.f;
    for (int i = 0; i < 128; ++i) { acc += red[i]; sn += sp_sum[i]; }
    float pena = fmaxf(trans[2] - trans[0], 0.f) + fmaxf(trans[1] - trans[3], 0.f);
    out[0] = acc / 128.f;
    out[1] = 0.1f * pena + 0.1f * (sn / 128.f);
  }
}

// ---------------- launcher ----------------
extern "C" void kernel_launch(void* const* d_in, const int* in_sizes, int n_in,
                              void* d_out, int out_size, void* d_ws, size_t ws_size,
                              hipStream_t stream) {
  const int*   sents  = (const int*)d_in[0];
  const int*   lens   = (const int*)d_in[1];
  const int*   masks  = (const int*)d_in[2];
  const int*   labels = (const int*)d_in[3];
  const float* wemb   = (const float*)d_in[4];
  const float* memb   = (const float*)d_in[5];
  const float* wih0f = (const float*)d_in[6],  *whh0f = (const float*)d_in[7];
  const float* bih0f = (const float*)d_in[8],  *bhh0f = (const float*)d_in[9];
  const float* wih0b = (const float*)d_in[10], *whh0b = (const float*)d_in[11];
  const float* bih0b = (const float*)d_in[12], *bhh0b = (const float*)d_in[13];
  const float* wih1f = (const float*)d_in[14], *whh1f = (const float*)d_in[15];
  const float* bih1f = (const float*)d_in[16], *bhh1f = (const float*)d_in[17];
  const float* wih1b = (const float*)d_in[18], *whh1b = (const float*)d_in[19];
  const float* bih1b = (const float*)d_in[20], *bhh1b = (const float*)d_in[21];
  const float* convw = (const float*)d_in[22], *convb = (const float*)d_in[23];
  const float* triw  = (const float*)d_in[24], *trib  = (const float*)d_in[25];
  const float* trans = (const float*)d_in[26];
  const float* labw  = (const float*)d_in[27], *labb  = (const float*)d_in[28];
  float* out = (float*)d_out;
  char* ws = (char*)d_ws;

  s16* x0    = (s16*)(ws + 0);
  s16* cwih0f = (s16*)(ws + 9011200);
  s16* cwih0b = (s16*)(ws + 9551872);
  s16* cwih1f = (s16*)(ws + 10092544);
  s16* cwih1b = (s16*)(ws + 10878976);
  s16* wf0f  = (s16*)(ws + 11665408);
  s16* wf0b  = (s16*)(ws + 12058624);
  s16* wf1f  = (s16*)(ws + 12451840);
  s16* wf1b  = (s16*)(ws + 12845056);
  s16* w2    = (s16*)(ws + 13238272);
  s16* giF   = (s16*)(ws + 14811136);
  s16* giB   = (s16*)(ws + 34471936);
  s16* x1    = (s16*)(ws + 54132736);
  s16* x2    = (s16*)(ws + 67239936);
  s16* A2    = giF;            // alias: gi dead after gru1
  s16* ctx   = x1;             // alias: x1 dead after gi1 GEMMs
  float* avg   = (float*)(ws + 80347136);
  float* tri   = (float*)(ws + 80609280);
  float* alphas= (float*)(ws + 80711680);
  float* sp    = (float*)(ws + 80814080);
  float* spsum = (float*)(ws + 80865280);
  float* sentv = (float*)(ws + 80865792);
  float* cb0f  = (float*)(ws + 81127936);
  float* cb0b  = (float*)(ws + 81131008);
  float* cb1f  = (float*)(ws + 81134080);
  float* cb1b  = (float*)(ws + 81137152);

  // fused prep
  k_prep<<<2048, 256, 0, stream>>>(wih0f, wih0b, wih1f, wih1b,
                                   whh0f, whh0b, whh1f, whh1b, convw,
                                   sents, masks, wemb, memb,
                                   bih0f, bhh0f, bih0b, bhh0b,
                                   bih1f, bhh1f, bih1b, bhh1b,
                                   cwih0f, cwih0b, cwih1f, cwih1b,
                                   wf0f, wf0b, wf1f, wf1b, w2, x0, (uint4*)x2,
                                   cb0f, cb0b, cb1f, cb1b);

  // layer 0 (merged bih+bhh bias)
  k_gemm<<<dim3(100, 6), 256, 0, stream>>>(x0, cwih0f, giF, 352, 352, 352, 768, cb0f, 0);
  k_gemm<<<dim3(100, 6), 256, 0, stream>>>(x0, cwih0b, giB, 352, 352, 352, 768, cb0b, 0);
  k_gru<<<dim3(32, 2), 512, 0, stream>>>(giF, giB, wf0f, wf0b, bhh0f, bhh0b, lens, x1);

  // layer 1
  k_gemm<<<dim3(100, 6), 256, 0, stream>>>(x1, cwih1f, giF, 512, 512, 512, 768, cb1f, 0);
  k_gemm<<<dim3(100, 6), 256, 0, stream>>>(x1, cwih1b, giB, 512, 512, 512, 768, cb1b, 0);
  k_gru<<<dim3(32, 2), 512, 0, stream>>>(giF, giB, wf1f, wf1b, bhh1f, bhh1b, lens, x2);

  // conv + epilogue
  k_im2col<<<9600, 256, 0, stream>>>(x2, A2);
  k_gemm<<<dim3(100, 4), 256, 0, stream>>>(A2, w2, ctx, 1536, 1536, 1536, 512, convb, 1);
  k_avg<<<128, 256, 0, stream>>>(ctx, masks, avg);
  k_tri<<<3200, 256, 0, stream>>>(ctx, avg, triw, trib, tri);
  k_crf<<<1, 128, 0, stream>>>(tri, lens, trans, alphas, sp, spsum);
  k_sentv<<<128, 256, 0, stream>>>(ctx, sp, sentv);
  k_final<<<1, 128, 0, stream>>>(sentv, spsum, labels, labw, labb, trans, out);
}